// Round 1
// baseline (563.759 us; speedup 1.0000x reference)
//
#include <hip/hip_runtime.h>
#include <stdint.h>

typedef unsigned short u16;
typedef short bf16x8 __attribute__((ext_vector_type(8)));
typedef float f32x4 __attribute__((ext_vector_type(4)));
typedef u16 u16x4 __attribute__((ext_vector_type(4)));
typedef u16 u16x8 __attribute__((ext_vector_type(8)));

#define B_SZ   1024
#define D_IN   400
#define L_OUT  392
#define OC     32
#define KW     9
#define K_FC   12544   /* OC*L_OUT */
#define N_ENT  50000
#define KPAD_H 448     /* 400 -> 7*64 */
#define NPAD_FC 512    /* 400 -> 4*128 */
#define SPLIT_FC 14    /* 196 ksteps = 14*14, perfectly balanced */

__device__ __forceinline__ u16 f2bf(float f) {
  uint32_t u = __builtin_bit_cast(uint32_t, f);
  u += 0x7FFFu + ((u >> 16) & 1u);
  return (u16)(u >> 16);
}
__device__ __forceinline__ float bf2f(u16 v) {
  uint32_t u = ((uint32_t)v) << 16;
  return __builtin_bit_cast(float, u);
}

__device__ __forceinline__ void gload_lds16(const u16* g, u16* l) {
  __builtin_amdgcn_global_load_lds(
      (const __attribute__((address_space(1))) unsigned int*)g,
      (__attribute__((address_space(3))) unsigned int*)l, 16, 0, 0);
}

// reduce (s1,s2) across a 256-thread block; result valid in thread 0 only
__device__ __forceinline__ void block_reduce2(float& s1, float& s2, float* sm) {
  for (int d = 32; d; d >>= 1) { s1 += __shfl_down(s1, d); s2 += __shfl_down(s2, d); }
  int wave = threadIdx.x >> 6, lane = threadIdx.x & 63;
  if (lane == 0) { sm[wave * 2] = s1; sm[wave * 2 + 1] = s2; }
  __syncthreads();
  if (threadIdx.x == 0) {
    s1 = sm[0] + sm[2] + sm[4] + sm[6];
    s2 = sm[1] + sm[3] + sm[5] + sm[7];
  }
}

// ---------- bn0 stage (partial sums) ----------
__global__ __launch_bounds__(256) void red0(const float* __restrict__ e1, float* __restrict__ part0) {
  int t = threadIdx.x;
  int idx = blockIdx.x * 256 + t;
  float s1 = 0.f, s2 = 0.f;
  for (int i = idx; i < B_SZ * D_IN; i += 256 * 256) { float v = e1[i]; s1 += v; s2 += v * v; }
  __shared__ float sm[8];
  block_reduce2(s1, s2, sm);
  if (t == 0) { part0[blockIdx.x * 2] = s1; part0[blockIdx.x * 2 + 1] = s2; }
}

// ---------- fc1: k = rel @ fc1_w^T + fc1_b  (fp32, tiny) + fused bn0 combine ----------
__global__ __launch_bounds__(256) void fc1_gemm(const float* __restrict__ rel,
                                                const float* __restrict__ W,
                                                const float* __restrict__ bias,
                                                float* __restrict__ outk,
                                                const float* __restrict__ part0,
                                                const float* __restrict__ g0,
                                                const float* __restrict__ b0,
                                                float* __restrict__ stats) {
  __shared__ __align__(16) float As[16 * 68];
  __shared__ __align__(16) float Bs[16 * 68];
  __shared__ float sm0[8];
  int mt = blockIdx.x, nt = blockIdx.y;
  int t = threadIdx.x;
  int tx = t & 15, ty = t >> 4;
  int lr = t >> 2, lk = (t & 3) * 4;
  float acc[4][4] = {};
  for (int k0 = 0; k0 < 400; k0 += 16) {
    __syncthreads();
    float4 av = *(const float4*)(rel + (size_t)(mt * 64 + lr) * 400 + k0 + lk);
    int brow = nt * 64 + lr;
    float4 bv = {0.f, 0.f, 0.f, 0.f};
    if (brow < 288) bv = *(const float4*)(W + (size_t)brow * 400 + k0 + lk);
    As[(lk + 0) * 68 + lr] = av.x; As[(lk + 1) * 68 + lr] = av.y;
    As[(lk + 2) * 68 + lr] = av.z; As[(lk + 3) * 68 + lr] = av.w;
    Bs[(lk + 0) * 68 + lr] = bv.x; Bs[(lk + 1) * 68 + lr] = bv.y;
    Bs[(lk + 2) * 68 + lr] = bv.z; Bs[(lk + 3) * 68 + lr] = bv.w;
    __syncthreads();
#pragma unroll
    for (int k = 0; k < 16; ++k) {
      float4 a = *(const float4*)(As + k * 68 + ty * 4);
      float4 b = *(const float4*)(Bs + k * 68 + tx * 4);
      float aa[4] = {a.x, a.y, a.z, a.w}, bb[4] = {b.x, b.y, b.z, b.w};
#pragma unroll
      for (int i = 0; i < 4; ++i)
#pragma unroll
        for (int j = 0; j < 4; ++j) acc[i][j] += aa[i] * bb[j];
    }
  }
#pragma unroll
  for (int i = 0; i < 4; ++i) {
    int row = mt * 64 + ty * 4 + i;
#pragma unroll
    for (int j = 0; j < 4; ++j) {
      int col = nt * 64 + tx * 4 + j;
      if (col < 288) outk[(size_t)row * 288 + col] = acc[i][j] + bias[col];
    }
  }
  // fused bn0 combine (one block does it; runs in parallel with other blocks' GEMM)
  if (mt == 0 && nt == 0) {
    float s1 = part0[t * 2], s2 = part0[t * 2 + 1];
    __syncthreads();
    block_reduce2(s1, s2, sm0);
    if (t == 0) {
      const float N = (float)(B_SZ * D_IN);
      float mu = s1 / N, var = s2 / N - mu * mu;
      float a = g0[0] * rsqrtf(var + 1e-5f);
      stats[0] = a;
      stats[1] = b0[0] - mu * a;
    }
  }
}

// ---------- conv + bn1 partial stats; raw conv stored as bf16 ----------
__global__ __launch_bounds__(256) void conv_kernel(const float* __restrict__ e1,
                                                   const float* __restrict__ stats,
                                                   const float* __restrict__ kbuf,
                                                   u16* __restrict__ convA,
                                                   float* __restrict__ partial1) {
  int b = blockIdx.x, t = threadIdx.x;
  __shared__ __align__(16) float xs[D_IN];
  __shared__ float ks[OC * KW];
  float a0 = stats[0], b0c = stats[1];
  for (int i = t; i < D_IN; i += 256) xs[i] = e1[(size_t)b * D_IN + i] * a0 + b0c;
  for (int i = t; i < OC * KW; i += 256) ks[i] = kbuf[(size_t)b * (OC * KW) + i];
  __syncthreads();
  int o = t >> 3, sub = t & 7;
  float kw[KW];
#pragma unroll
  for (int w = 0; w < KW; ++w) kw[w] = ks[o * KW + w];
  float s1 = 0.f, s2 = 0.f;
  u16* orow = convA + (size_t)b * K_FC + o * L_OUT;
#pragma unroll
  for (int it = 0; it < 13; ++it) {
    int l = sub * 4 + it * 32;
    if (l < L_OUT) {
      float4 x0 = *(const float4*)(xs + l);
      float4 x1 = *(const float4*)(xs + l + 4);
      float4 x2 = *(const float4*)(xs + l + 8);
      float xv[12] = {x0.x, x0.y, x0.z, x0.w, x1.x, x1.y, x1.z, x1.w, x2.x, x2.y, x2.z, x2.w};
      u16x4 st;
#pragma unroll
      for (int j = 0; j < 4; ++j) {
        float c = 0.f;
#pragma unroll
        for (int w = 0; w < KW; ++w) c += xv[j + w] * kw[w];
        s1 += c; s2 += c * c;
        st[j] = f2bf(c);
      }
      *(u16x4*)(orow + l) = st;
    }
  }
  s1 += __shfl_down(s1, 4); s2 += __shfl_down(s2, 4);
  s1 += __shfl_down(s1, 2); s2 += __shfl_down(s2, 2);
  s1 += __shfl_down(s1, 1); s2 += __shfl_down(s2, 1);
  if (sub == 0) {
    partial1[b * 64 + o] = s1;
    partial1[b * 64 + 32 + o] = s2;
  }
}

// ---------- bn1 combine -> expanded alpha over k (beta cancels under bn2) ----------
__global__ __launch_bounds__(256) void comb1(const float* __restrict__ partial1,
                                             const float* __restrict__ g1,
                                             float* __restrict__ alphaK) {
  __shared__ float red[256];
  __shared__ float ab[32];
  int t = threadIdx.x;
  int s = t & 63, q = t >> 6;
  float acc = 0.f;
  for (int b = q * 256; b < q * 256 + 256; ++b) acc += partial1[b * 64 + s];
  red[t] = acc;
  __syncthreads();
  if (t < 64) red[t] = red[t] + red[t + 64] + red[t + 128] + red[t + 192];
  __syncthreads();
  if (t < 32) {
    const float N = (float)(B_SZ * L_OUT);
    float S1 = red[t], S2 = red[t + 32];
    float mu = S1 / N, var = S2 / N - mu * mu;
    ab[t] = g1[t] * rsqrtf(var + 1e-5f);
  }
  __syncthreads();
  for (int i = t; i < K_FC; i += 256) {
    int o = i / L_OUT;
    alphaK[i] = ab[o];
  }
}

// ---------- converter: fc weights * alphaK -> bf16 (bn1 alpha folded) ----------
__global__ __launch_bounds__(256) void cvt_fcw(const float* __restrict__ src,
                                               const float* __restrict__ alphaK,
                                               u16* __restrict__ dst) {
  int gid = blockIdx.x * 256 + threadIdx.x;       // 512*1568 threads
  int row = gid / 1568, c = gid - row * 1568;
  int k = c * 8;
  u16x8 o = {};
  if (row < 400) {
    float4 f0 = *(const float4*)(src + (size_t)row * K_FC + k);
    float4 f1 = *(const float4*)(src + (size_t)row * K_FC + k + 4);
    float4 a0 = *(const float4*)(alphaK + k);
    float4 a1 = *(const float4*)(alphaK + k + 4);
    o[0] = f2bf(f0.x * a0.x); o[1] = f2bf(f0.y * a0.y);
    o[2] = f2bf(f0.z * a0.z); o[3] = f2bf(f0.w * a0.w);
    o[4] = f2bf(f1.x * a1.x); o[5] = f2bf(f1.y * a1.y);
    o[6] = f2bf(f1.z * a1.z); o[7] = f2bf(f1.w * a1.w);
  }
  *(u16x8*)(dst + (size_t)row * K_FC + k) = o;
}

// ---------- bn2 + relu -> hfin (bf16, padded to 448); coalesced ----------
__global__ __launch_bounds__(256) void bn2_kernel(const float* __restrict__ part2,
                                                  const float* __restrict__ g2,
                                                  const float* __restrict__ b2,
                                                  u16* __restrict__ hfin) {
  int j0 = blockIdx.x * 16;
  int t = threadIdx.x;
  int tj = t & 15, tb = t >> 4;
  int j = j0 + tj;
  float v[64];
  float s1 = 0.f, s2 = 0.f;
#pragma unroll 2
  for (int i = 0; i < 64; ++i) {
    int b = tb + i * 16;
    float acc = 0.f;
#pragma unroll
    for (int s = 0; s < SPLIT_FC; ++s)
      acc += part2[((size_t)s * B_SZ + b) * NPAD_FC + j];
    v[i] = acc; s1 += acc; s2 += acc * acc;
  }
  __shared__ float sm1[16][17], sm2[16][17];
  sm1[tb][tj] = s1; sm2[tb][tj] = s2;
  __syncthreads();
  __shared__ float albe[2][16];
  if (t < 16) {
    float S1 = 0.f, S2 = 0.f;
#pragma unroll
    for (int r = 0; r < 16; ++r) { S1 += sm1[r][t]; S2 += sm2[r][t]; }
    int jf = j0 + t;
    float al = 0.f, be = 0.f;
    if (jf < D_IN) {
      float mu = S1 / 1024.f, var = S2 / 1024.f - mu * mu;
      al = g2[jf] * rsqrtf(var + 1e-5f);
      be = b2[jf] - mu * al;
    }
    albe[0][t] = al; albe[1][t] = be;
  }
  __syncthreads();
  float al = albe[0][tj], be = albe[1][tj];
#pragma unroll 2
  for (int i = 0; i < 64; ++i) {
    int b = tb + i * 16;
    hfin[(size_t)b * KPAD_H + j] = f2bf(fmaxf(v[i] * al + be, 0.f));
  }
}

// ---------- bf16 MFMA GEMM: C = A[M,Kpad] @ B[N,Kpad]^T  (m97-style, fc stage) ----------
__global__ __launch_bounds__(256) void gemm_bt(const u16* __restrict__ A,
                                               const u16* __restrict__ Bm,
                                               float* __restrict__ C,
                                               int Kpad, int mtiles, int ntiles,
                                               int ksteps_total, int ksteps_chunk,
                                               long ldc, int ncols_valid, long csplit_stride) {
  __shared__ __align__(16) u16 As[128 * 64];
  __shared__ __align__(16) u16 Bs[128 * 64];
  int bid = blockIdx.x;
  int mt = bid % mtiles;
  int nt = (bid / mtiles) % ntiles;
  int sp = bid / (mtiles * ntiles);
  int kbeg = sp * ksteps_chunk;
  int kend = kbeg + ksteps_chunk;
  if (kend > ksteps_total) kend = ksteps_total;

  int tid = threadIdx.x;
  int wave = tid >> 6, lane = tid & 63;
  int quad = lane >> 4, m16 = lane & 15;
  int rbase = (wave >> 1) * 64, cbase = (wave & 1) * 64;

  const u16* Arow0 = A + (size_t)mt * 128 * Kpad;
  const u16* Brow0 = Bm + (size_t)nt * 128 * Kpad;

  f32x4 acc[4][4] = {};

  for (int kt = kbeg; kt < kend; ++kt) {
    int k0 = kt * 64;
    __syncthreads();
#pragma unroll
    for (int p = 0; p < 4; ++p) {
      int slin = p * 256 + tid;
      int row = slin >> 3;
      int gch = (slin & 7) ^ (row & 7);            // XOR-8 swizzle, conflict-free reads
      u16* la = As + ((p * 256 + (wave << 6)) << 3);
      u16* lb = Bs + ((p * 256 + (wave << 6)) << 3);
      gload_lds16(Arow0 + (size_t)row * Kpad + k0 + gch * 8, la);
      gload_lds16(Brow0 + (size_t)row * Kpad + k0 + gch * 8, lb);
    }
    __syncthreads();
#pragma unroll
    for (int s = 0; s < 2; ++s) {
      bf16x8 af[4], bfr[4];
#pragma unroll
      for (int i = 0; i < 4; ++i) {
        int ar = rbase + i * 16 + m16;
        af[i] = *(const bf16x8*)(As + ar * 64 + (((s * 4 + quad) ^ (ar & 7)) << 3));
        int bc = cbase + i * 16 + m16;
        bfr[i] = *(const bf16x8*)(Bs + bc * 64 + (((s * 4 + quad) ^ (bc & 7)) << 3));
      }
#pragma unroll
      for (int i = 0; i < 4; ++i)
#pragma unroll
        for (int j = 0; j < 4; ++j)
          acc[i][j] = __builtin_amdgcn_mfma_f32_16x16x32_bf16(af[i], bfr[j], acc[i][j], 0, 0, 0);
    }
  }

  float* Cb = C + (size_t)sp * csplit_stride;
#pragma unroll
  for (int i = 0; i < 4; ++i) {
#pragma unroll
    for (int j = 0; j < 4; ++j) {
      int col = nt * 128 + cbase + j * 16 + m16;
      if (col < ncols_valid) {
        int row0 = mt * 128 + rbase + i * 16 + quad * 4;
#pragma unroll
        for (int r = 0; r < 4; ++r)
          Cb[(size_t)(row0 + r) * ldc + col] = acc[i][j][r];
      }
    }
  }
}

// ---------- final GEMM: C = hfin[1024,448] @ entw[50000,400]^T, fused f32->bf16 B-staging ----------
// B is reg-staged from fp32 entw (global_load float4 -> f2bf -> ds_write_b128), producing the
// exact same swizzled LDS image (and bit-identical bf16 values) as the old cvt_ent+gload path.
// XCD swizzle: the 8 mt-blocks sharing an nt get the same bid%8 residue -> same XCD L2.
__global__ __launch_bounds__(256) void gemm_ent(const u16* __restrict__ A,
                                                const float* __restrict__ Bf,
                                                float* __restrict__ C) {
  __shared__ __align__(16) u16 As[128 * 64];
  __shared__ __align__(16) u16 Bs[128 * 64];
  int bid = blockIdx.x;
  int r = bid & 7, g = bid >> 3;
  int mt = g & 7;
  int nt = (g >> 3) * 8 + r;
  if (nt >= 391) return;

  int tid = threadIdx.x;
  int wave = tid >> 6, lane = tid & 63;
  int quad = lane >> 4, m16 = lane & 15;
  int rbase = (wave >> 1) * 64, cbase = (wave & 1) * 64;

  const u16* Arow0 = A + (size_t)mt * 128 * KPAD_H;

  f32x4 acc[4][4] = {};

  for (int kt = 0; kt < 7; ++kt) {
    int k0 = kt * 64;
    __syncthreads();
    // B: issue fp32 loads first (latency-critical), zeros outside [50000, 400)
    float4 fb[4][2];
#pragma unroll
    for (int p = 0; p < 4; ++p) {
      int slin = p * 256 + tid;
      int row = slin >> 3;
      int gch = (slin & 7) ^ (row & 7);            // pre-swizzled global source
      int gr = nt * 128 + row;
      int gk = k0 + gch * 8;                        // chunk-granular validity (400-384=16=2 chunks)
      if (gr < N_ENT && gk < D_IN) {
        fb[p][0] = *(const float4*)(Bf + (size_t)gr * D_IN + gk);
        fb[p][1] = *(const float4*)(Bf + (size_t)gr * D_IN + gk + 4);
      } else {
        fb[p][0] = float4{0.f, 0.f, 0.f, 0.f};
        fb[p][1] = float4{0.f, 0.f, 0.f, 0.f};
      }
    }
    // A: async global->LDS
#pragma unroll
    for (int p = 0; p < 4; ++p) {
      int slin = p * 256 + tid;
      int row = slin >> 3;
      int gch = (slin & 7) ^ (row & 7);
      u16* la = As + ((p * 256 + (wave << 6)) << 3);
      gload_lds16(Arow0 + (size_t)row * KPAD_H + k0 + gch * 8, la);
    }
    // B: convert + scatter to the same linear LDS slot the gload path used
#pragma unroll
    for (int p = 0; p < 4; ++p) {
      int slin = p * 256 + tid;
      u16x8 st;
      st[0] = f2bf(fb[p][0].x); st[1] = f2bf(fb[p][0].y);
      st[2] = f2bf(fb[p][0].z); st[3] = f2bf(fb[p][0].w);
      st[4] = f2bf(fb[p][1].x); st[5] = f2bf(fb[p][1].y);
      st[6] = f2bf(fb[p][1].z); st[7] = f2bf(fb[p][1].w);
      *(u16x8*)(Bs + slin * 8) = st;
    }
    __syncthreads();
#pragma unroll
    for (int s = 0; s < 2; ++s) {
      bf16x8 af[4], bfr[4];
#pragma unroll
      for (int i = 0; i < 4; ++i) {
        int ar = rbase + i * 16 + m16;
        af[i] = *(const bf16x8*)(As + ar * 64 + (((s * 4 + quad) ^ (ar & 7)) << 3));
        int bc = cbase + i * 16 + m16;
        bfr[i] = *(const bf16x8*)(Bs + bc * 64 + (((s * 4 + quad) ^ (bc & 7)) << 3));
      }
#pragma unroll
      for (int i = 0; i < 4; ++i)
#pragma unroll
        for (int j = 0; j < 4; ++j)
          acc[i][j] = __builtin_amdgcn_mfma_f32_16x16x32_bf16(af[i], bfr[j], acc[i][j], 0, 0, 0);
    }
  }

#pragma unroll
  for (int i = 0; i < 4; ++i) {
#pragma unroll
    for (int j = 0; j < 4; ++j) {
      int col = nt * 128 + cbase + j * 16 + m16;
      if (col < N_ENT) {
        int row0 = mt * 128 + rbase + i * 16 + quad * 4;
#pragma unroll
        for (int r = 0; r < 4; ++r)
          C[(size_t)(row0 + r) * N_ENT + col] = acc[i][j][r];
      }
    }
  }
}

extern "C" void kernel_launch(void* const* d_in, const int* in_sizes, int n_in,
                              void* d_out, int out_size, void* d_ws, size_t ws_size,
                              hipStream_t stream) {
  const float* e1   = (const float*)d_in[0];
  const float* rel  = (const float*)d_in[1];
  const float* entw = (const float*)d_in[2];
  const float* fc1w = (const float*)d_in[3];
  const float* fc1b = (const float*)d_in[4];
  const float* fcw  = (const float*)d_in[5];
  // d_in[6] = fc_b: constant per output feature -> cancels under bn2 mean subtraction
  const float* bn0g = (const float*)d_in[7];
  const float* bn0b = (const float*)d_in[8];
  const float* bn1g = (const float*)d_in[9];
  // d_in[10] = bn1_b: beta term is constant per k -> cancels under bn2 mean subtraction
  const float* bn2g = (const float*)d_in[11];
  const float* bn2b = (const float*)d_in[12];
  float* out = (float*)d_out;

  char* ws = (char*)d_ws;
  size_t off = 0;
  auto alloc = [&](size_t bytes) -> void* {
    off = (off + 255) & ~(size_t)255;
    void* p = ws + off;
    off += bytes;
    return p;
  };
  float* stats    = (float*)alloc(16 * 4);
  float* part0    = (float*)alloc(512 * 4);
  float* kbuf     = (float*)alloc((size_t)B_SZ * 288 * 4);
  float* partial1 = (float*)alloc((size_t)B_SZ * 64 * 4);
  float* alphaK   = (float*)alloc((size_t)K_FC * 4);
  u16*   convA    = (u16*)alloc((size_t)B_SZ * K_FC * 2);
  u16*   fcwb     = (u16*)alloc((size_t)NPAD_FC * K_FC * 2);
  float* part2    = (float*)alloc((size_t)SPLIT_FC * B_SZ * NPAD_FC * 4);
  u16*   hfin     = (u16*)alloc((size_t)B_SZ * KPAD_H * 2);

  red0<<<256, 256, 0, stream>>>(e1, part0);
  // fc1 GEMM with fused bn0-combine (block 0 tail)
  fc1_gemm<<<dim3(16, 5), 256, 0, stream>>>(rel, fc1w, fc1b, kbuf, part0, bn0g, bn0b, stats);
  conv_kernel<<<B_SZ, 256, 0, stream>>>(e1, stats, kbuf, convA, partial1);
  comb1<<<1, 256, 0, stream>>>(partial1, bn1g, alphaK);
  cvt_fcw<<<3136, 256, 0, stream>>>(fcw, alphaK, fcwb);
  // fc GEMM: M=1024, N=512(pad of 400), K=12544 -> split-K=14 deterministic partials
  gemm_bt<<<8 * 4 * SPLIT_FC, 256, 0, stream>>>(convA, fcwb, part2, K_FC, 8, 4, 196, 14,
                                                (long)NPAD_FC, NPAD_FC, (long)B_SZ * NPAD_FC);
  bn2_kernel<<<KPAD_H / 16, 256, 0, stream>>>(part2, bn2g, bn2b, hfin);
  // final GEMM: M=1024, N=50048(pad of 50000), K=448(pad of 400), XCD-swizzled,
  // with the entity-weight f32->bf16 conversion fused into B-staging (cvt_ent removed)
  gemm_ent<<<8 * 392, 256, 0, stream>>>(hfin, entw, out);
}

// Round 2
// 551.059 us; speedup vs baseline: 1.0230x; 1.0230x over previous
//
#include <hip/hip_runtime.h>
#include <stdint.h>

typedef unsigned short u16;
typedef short bf16x8 __attribute__((ext_vector_type(8)));
typedef float f32x4 __attribute__((ext_vector_type(4)));
typedef u16 u16x4 __attribute__((ext_vector_type(4)));
typedef u16 u16x8 __attribute__((ext_vector_type(8)));

#define B_SZ   1024
#define D_IN   400
#define L_OUT  392
#define OC     32
#define KW     9
#define K_FC   12544   /* OC*L_OUT */
#define N_ENT  50000
#define KPAD_H 448     /* 400 -> 7*64 */
#define NPAD_FC 512    /* 400 -> 4*128 */
#define SPLIT_FC 14    /* 196 ksteps = 14*14, perfectly balanced */

__device__ __forceinline__ u16 f2bf(float f) {
  uint32_t u = __builtin_bit_cast(uint32_t, f);
  u += 0x7FFFu + ((u >> 16) & 1u);
  return (u16)(u >> 16);
}
__device__ __forceinline__ float bf2f(u16 v) {
  uint32_t u = ((uint32_t)v) << 16;
  return __builtin_bit_cast(float, u);
}

__device__ __forceinline__ void gload_lds16(const u16* g, u16* l) {
  __builtin_amdgcn_global_load_lds(
      (const __attribute__((address_space(1))) unsigned int*)g,
      (__attribute__((address_space(3))) unsigned int*)l, 16, 0, 0);
}

// reduce (s1,s2) across a 256-thread block; result valid in thread 0 only
__device__ __forceinline__ void block_reduce2(float& s1, float& s2, float* sm) {
  for (int d = 32; d; d >>= 1) { s1 += __shfl_down(s1, d); s2 += __shfl_down(s2, d); }
  int wave = threadIdx.x >> 6, lane = threadIdx.x & 63;
  if (lane == 0) { sm[wave * 2] = s1; sm[wave * 2 + 1] = s2; }
  __syncthreads();
  if (threadIdx.x == 0) {
    s1 = sm[0] + sm[2] + sm[4] + sm[6];
    s2 = sm[1] + sm[3] + sm[5] + sm[7];
  }
}

// ---------- bn0 stage (partial sums) ----------
__global__ __launch_bounds__(256) void red0(const float* __restrict__ e1, float* __restrict__ part0) {
  int t = threadIdx.x;
  int idx = blockIdx.x * 256 + t;
  float s1 = 0.f, s2 = 0.f;
  for (int i = idx; i < B_SZ * D_IN; i += 256 * 256) { float v = e1[i]; s1 += v; s2 += v * v; }
  __shared__ float sm[8];
  block_reduce2(s1, s2, sm);
  if (t == 0) { part0[blockIdx.x * 2] = s1; part0[blockIdx.x * 2 + 1] = s2; }
}

// ---------- fc1: k = rel @ fc1_w^T + fc1_b  (fp32, tiny) + fused bn0 combine ----------
__global__ __launch_bounds__(256) void fc1_gemm(const float* __restrict__ rel,
                                                const float* __restrict__ W,
                                                const float* __restrict__ bias,
                                                float* __restrict__ outk,
                                                const float* __restrict__ part0,
                                                const float* __restrict__ g0,
                                                const float* __restrict__ b0,
                                                float* __restrict__ stats) {
  __shared__ __align__(16) float As[16 * 68];
  __shared__ __align__(16) float Bs[16 * 68];
  __shared__ float sm0[8];
  int mt = blockIdx.x, nt = blockIdx.y;
  int t = threadIdx.x;
  int tx = t & 15, ty = t >> 4;
  int lr = t >> 2, lk = (t & 3) * 4;
  float acc[4][4] = {};
  for (int k0 = 0; k0 < 400; k0 += 16) {
    __syncthreads();
    float4 av = *(const float4*)(rel + (size_t)(mt * 64 + lr) * 400 + k0 + lk);
    int brow = nt * 64 + lr;
    float4 bv = {0.f, 0.f, 0.f, 0.f};
    if (brow < 288) bv = *(const float4*)(W + (size_t)brow * 400 + k0 + lk);
    As[(lk + 0) * 68 + lr] = av.x; As[(lk + 1) * 68 + lr] = av.y;
    As[(lk + 2) * 68 + lr] = av.z; As[(lk + 3) * 68 + lr] = av.w;
    Bs[(lk + 0) * 68 + lr] = bv.x; Bs[(lk + 1) * 68 + lr] = bv.y;
    Bs[(lk + 2) * 68 + lr] = bv.z; Bs[(lk + 3) * 68 + lr] = bv.w;
    __syncthreads();
#pragma unroll
    for (int k = 0; k < 16; ++k) {
      float4 a = *(const float4*)(As + k * 68 + ty * 4);
      float4 b = *(const float4*)(Bs + k * 68 + tx * 4);
      float aa[4] = {a.x, a.y, a.z, a.w}, bb[4] = {b.x, b.y, b.z, b.w};
#pragma unroll
      for (int i = 0; i < 4; ++i)
#pragma unroll
        for (int j = 0; j < 4; ++j) acc[i][j] += aa[i] * bb[j];
    }
  }
#pragma unroll
  for (int i = 0; i < 4; ++i) {
    int row = mt * 64 + ty * 4 + i;
#pragma unroll
    for (int j = 0; j < 4; ++j) {
      int col = nt * 64 + tx * 4 + j;
      if (col < 288) outk[(size_t)row * 288 + col] = acc[i][j] + bias[col];
    }
  }
  // fused bn0 combine (one block does it; runs in parallel with other blocks' GEMM)
  if (mt == 0 && nt == 0) {
    float s1 = part0[t * 2], s2 = part0[t * 2 + 1];
    __syncthreads();
    block_reduce2(s1, s2, sm0);
    if (t == 0) {
      const float N = (float)(B_SZ * D_IN);
      float mu = s1 / N, var = s2 / N - mu * mu;
      float a = g0[0] * rsqrtf(var + 1e-5f);
      stats[0] = a;
      stats[1] = b0[0] - mu * a;
    }
  }
}

// ---------- conv + bn1 partial stats; raw conv stored as bf16 ----------
__global__ __launch_bounds__(256) void conv_kernel(const float* __restrict__ e1,
                                                   const float* __restrict__ stats,
                                                   const float* __restrict__ kbuf,
                                                   u16* __restrict__ convA,
                                                   float* __restrict__ partial1) {
  int b = blockIdx.x, t = threadIdx.x;
  __shared__ __align__(16) float xs[D_IN];
  __shared__ float ks[OC * KW];
  float a0 = stats[0], b0c = stats[1];
  for (int i = t; i < D_IN; i += 256) xs[i] = e1[(size_t)b * D_IN + i] * a0 + b0c;
  for (int i = t; i < OC * KW; i += 256) ks[i] = kbuf[(size_t)b * (OC * KW) + i];
  __syncthreads();
  int o = t >> 3, sub = t & 7;
  float kw[KW];
#pragma unroll
  for (int w = 0; w < KW; ++w) kw[w] = ks[o * KW + w];
  float s1 = 0.f, s2 = 0.f;
  u16* orow = convA + (size_t)b * K_FC + o * L_OUT;
#pragma unroll
  for (int it = 0; it < 13; ++it) {
    int l = sub * 4 + it * 32;
    if (l < L_OUT) {
      float4 x0 = *(const float4*)(xs + l);
      float4 x1 = *(const float4*)(xs + l + 4);
      float4 x2 = *(const float4*)(xs + l + 8);
      float xv[12] = {x0.x, x0.y, x0.z, x0.w, x1.x, x1.y, x1.z, x1.w, x2.x, x2.y, x2.z, x2.w};
      u16x4 st;
#pragma unroll
      for (int j = 0; j < 4; ++j) {
        float c = 0.f;
#pragma unroll
        for (int w = 0; w < KW; ++w) c += xv[j + w] * kw[w];
        s1 += c; s2 += c * c;
        st[j] = f2bf(c);
      }
      *(u16x4*)(orow + l) = st;
    }
  }
  s1 += __shfl_down(s1, 4); s2 += __shfl_down(s2, 4);
  s1 += __shfl_down(s1, 2); s2 += __shfl_down(s2, 2);
  s1 += __shfl_down(s1, 1); s2 += __shfl_down(s2, 1);
  if (sub == 0) {
    partial1[b * 64 + o] = s1;
    partial1[b * 64 + 32 + o] = s2;
  }
}

// ---------- bn1 combine -> expanded alpha over k (beta cancels under bn2) ----------
__global__ __launch_bounds__(256) void comb1(const float* __restrict__ partial1,
                                             const float* __restrict__ g1,
                                             float* __restrict__ alphaK) {
  __shared__ float red[256];
  __shared__ float ab[32];
  int t = threadIdx.x;
  int s = t & 63, q = t >> 6;
  float acc = 0.f;
  for (int b = q * 256; b < q * 256 + 256; ++b) acc += partial1[b * 64 + s];
  red[t] = acc;
  __syncthreads();
  if (t < 64) red[t] = red[t] + red[t + 64] + red[t + 128] + red[t + 192];
  __syncthreads();
  if (t < 32) {
    const float N = (float)(B_SZ * L_OUT);
    float S1 = red[t], S2 = red[t + 32];
    float mu = S1 / N, var = S2 / N - mu * mu;
    ab[t] = g1[t] * rsqrtf(var + 1e-5f);
  }
  __syncthreads();
  for (int i = t; i < K_FC; i += 256) {
    int o = i / L_OUT;
    alphaK[i] = ab[o];
  }
}

// ---------- converter: fc weights * alphaK -> bf16 (bn1 alpha folded) ----------
__global__ __launch_bounds__(256) void cvt_fcw(const float* __restrict__ src,
                                               const float* __restrict__ alphaK,
                                               u16* __restrict__ dst) {
  int gid = blockIdx.x * 256 + threadIdx.x;       // 512*1568 threads
  int row = gid / 1568, c = gid - row * 1568;
  int k = c * 8;
  u16x8 o = {};
  if (row < 400) {
    float4 f0 = *(const float4*)(src + (size_t)row * K_FC + k);
    float4 f1 = *(const float4*)(src + (size_t)row * K_FC + k + 4);
    float4 a0 = *(const float4*)(alphaK + k);
    float4 a1 = *(const float4*)(alphaK + k + 4);
    o[0] = f2bf(f0.x * a0.x); o[1] = f2bf(f0.y * a0.y);
    o[2] = f2bf(f0.z * a0.z); o[3] = f2bf(f0.w * a0.w);
    o[4] = f2bf(f1.x * a1.x); o[5] = f2bf(f1.y * a1.y);
    o[6] = f2bf(f1.z * a1.z); o[7] = f2bf(f1.w * a1.w);
  }
  *(u16x8*)(dst + (size_t)row * K_FC + k) = o;
}

// ---------- bn2 + relu -> hfin (bf16, padded to 448); coalesced ----------
__global__ __launch_bounds__(256) void bn2_kernel(const float* __restrict__ part2,
                                                  const float* __restrict__ g2,
                                                  const float* __restrict__ b2,
                                                  u16* __restrict__ hfin) {
  int j0 = blockIdx.x * 16;
  int t = threadIdx.x;
  int tj = t & 15, tb = t >> 4;
  int j = j0 + tj;
  float v[64];
  float s1 = 0.f, s2 = 0.f;
#pragma unroll 2
  for (int i = 0; i < 64; ++i) {
    int b = tb + i * 16;
    float acc = 0.f;
#pragma unroll
    for (int s = 0; s < SPLIT_FC; ++s)
      acc += part2[((size_t)s * B_SZ + b) * NPAD_FC + j];
    v[i] = acc; s1 += acc; s2 += acc * acc;
  }
  __shared__ float sm1[16][17], sm2[16][17];
  sm1[tb][tj] = s1; sm2[tb][tj] = s2;
  __syncthreads();
  __shared__ float albe[2][16];
  if (t < 16) {
    float S1 = 0.f, S2 = 0.f;
#pragma unroll
    for (int r = 0; r < 16; ++r) { S1 += sm1[r][t]; S2 += sm2[r][t]; }
    int jf = j0 + t;
    float al = 0.f, be = 0.f;
    if (jf < D_IN) {
      float mu = S1 / 1024.f, var = S2 / 1024.f - mu * mu;
      al = g2[jf] * rsqrtf(var + 1e-5f);
      be = b2[jf] - mu * al;
    }
    albe[0][t] = al; albe[1][t] = be;
  }
  __syncthreads();
  float al = albe[0][tj], be = albe[1][tj];
#pragma unroll 2
  for (int i = 0; i < 64; ++i) {
    int b = tb + i * 16;
    hfin[(size_t)b * KPAD_H + j] = f2bf(fmaxf(v[i] * al + be, 0.f));
  }
}

// ---------- bf16 MFMA GEMM: C = A[M,Kpad] @ B[N,Kpad]^T  (m97-style, fc stage) ----------
__global__ __launch_bounds__(256) void gemm_bt(const u16* __restrict__ A,
                                               const u16* __restrict__ Bm,
                                               float* __restrict__ C,
                                               int Kpad, int mtiles, int ntiles,
                                               int ksteps_total, int ksteps_chunk,
                                               long ldc, int ncols_valid, long csplit_stride) {
  __shared__ __align__(16) u16 As[128 * 64];
  __shared__ __align__(16) u16 Bs[128 * 64];
  int bid = blockIdx.x;
  int mt = bid % mtiles;
  int nt = (bid / mtiles) % ntiles;
  int sp = bid / (mtiles * ntiles);
  int kbeg = sp * ksteps_chunk;
  int kend = kbeg + ksteps_chunk;
  if (kend > ksteps_total) kend = ksteps_total;

  int tid = threadIdx.x;
  int wave = tid >> 6, lane = tid & 63;
  int quad = lane >> 4, m16 = lane & 15;
  int rbase = (wave >> 1) * 64, cbase = (wave & 1) * 64;

  const u16* Arow0 = A + (size_t)mt * 128 * Kpad;
  const u16* Brow0 = Bm + (size_t)nt * 128 * Kpad;

  f32x4 acc[4][4] = {};

  for (int kt = kbeg; kt < kend; ++kt) {
    int k0 = kt * 64;
    __syncthreads();
#pragma unroll
    for (int p = 0; p < 4; ++p) {
      int slin = p * 256 + tid;
      int row = slin >> 3;
      int gch = (slin & 7) ^ (row & 7);            // XOR-8 swizzle, conflict-free reads
      u16* la = As + ((p * 256 + (wave << 6)) << 3);
      u16* lb = Bs + ((p * 256 + (wave << 6)) << 3);
      gload_lds16(Arow0 + (size_t)row * Kpad + k0 + gch * 8, la);
      gload_lds16(Brow0 + (size_t)row * Kpad + k0 + gch * 8, lb);
    }
    __syncthreads();
#pragma unroll
    for (int s = 0; s < 2; ++s) {
      bf16x8 af[4], bfr[4];
#pragma unroll
      for (int i = 0; i < 4; ++i) {
        int ar = rbase + i * 16 + m16;
        af[i] = *(const bf16x8*)(As + ar * 64 + (((s * 4 + quad) ^ (ar & 7)) << 3));
        int bc = cbase + i * 16 + m16;
        bfr[i] = *(const bf16x8*)(Bs + bc * 64 + (((s * 4 + quad) ^ (bc & 7)) << 3));
      }
#pragma unroll
      for (int i = 0; i < 4; ++i)
#pragma unroll
        for (int j = 0; j < 4; ++j)
          acc[i][j] = __builtin_amdgcn_mfma_f32_16x16x32_bf16(af[i], bfr[j], acc[i][j], 0, 0, 0);
    }
  }

  float* Cb = C + (size_t)sp * csplit_stride;
#pragma unroll
  for (int i = 0; i < 4; ++i) {
#pragma unroll
    for (int j = 0; j < 4; ++j) {
      int col = nt * 128 + cbase + j * 16 + m16;
      if (col < ncols_valid) {
        int row0 = mt * 128 + rbase + i * 16 + quad * 4;
#pragma unroll
        for (int r = 0; r < 4; ++r)
          Cb[(size_t)(row0 + r) * ldc + col] = acc[i][j][r];
      }
    }
  }
}

// ---------- final GEMM v2: C = hfin[1024,448] @ entw[50000,400]^T ----------
// BM=256 x BN=128 (B re-read 4x not 8x), software-pipelined:
//   A (bf16, L2-resident) double-buffered via global_load_lds, prefetch dist 1
//   B (fp32) reg-staged with prefetch dist 1, f2bf + ds_write at step top
//   raw s_barrier + counted vmcnt(16) -> prefetch stays in flight across barriers
// Issue order per step: [... A(kt) x8 | B(kt+1) x8, A(kt+1) x8] => wait vmcnt(16)
// guarantees A(kt) landed. Same XOR-8 swizzle + K-order => bit-identical output.
__global__ __launch_bounds__(256, 2) void gemm_ent(const u16* __restrict__ A,
                                                   const float* __restrict__ Bf,
                                                   float* __restrict__ C) {
  __shared__ __align__(16) u16 As[2][256 * 64];
  __shared__ __align__(16) u16 Bs[128 * 64];
  int bid = blockIdx.x;
  int r = bid & 7, g = bid >> 3;
  int mt = g & 3;
  int nt = (g >> 2) * 8 + r;    // all 4 mt-blocks of an nt share bid%8 -> same XCD L2
  if (nt >= 391) return;

  int tid = threadIdx.x;
  int wave = tid >> 6, lane = tid & 63;
  int quad = lane >> 4, m16 = lane & 15;
  int rbase = (wave >> 1) * 128, cbase = (wave & 1) * 64;

  const u16* Arow0 = A + (size_t)mt * 256 * KPAD_H;

  float4 fb[4][2];

  // ---- staging helpers (unrolled, compile-time) ----
#define LOAD_B(K0)                                                         \
  {                                                                        \
    _Pragma("unroll") for (int q = 0; q < 4; ++q) {                        \
      int slin = q * 256 + tid;                                            \
      int row = slin >> 3;                                                 \
      int gch = (slin & 7) ^ (row & 7);                                    \
      int gr = nt * 128 + row;                                             \
      int gk = (K0) + gch * 8;                                             \
      if (gr < N_ENT && gk < D_IN) {                                       \
        fb[q][0] = *(const float4*)(Bf + (size_t)gr * D_IN + gk);          \
        fb[q][1] = *(const float4*)(Bf + (size_t)gr * D_IN + gk + 4);      \
      } else {                                                             \
        fb[q][0] = float4{0.f, 0.f, 0.f, 0.f};                             \
        fb[q][1] = float4{0.f, 0.f, 0.f, 0.f};                             \
      }                                                                    \
    }                                                                      \
  }

#define STAGE_A(KT, BUF)                                                   \
  {                                                                        \
    _Pragma("unroll") for (int p = 0; p < 8; ++p) {                        \
      int slin = p * 256 + tid;                                            \
      int row = slin >> 3;                                                 \
      int gch = (slin & 7) ^ (row & 7);                                    \
      u16* la = As[BUF] + ((p * 256 + (wave << 6)) << 3);                  \
      gload_lds16(Arow0 + (size_t)row * KPAD_H + (KT) * 64 + gch * 8, la); \
    }                                                                      \
  }

#define WRITE_B()                                                          \
  {                                                                        \
    _Pragma("unroll") for (int q = 0; q < 4; ++q) {                        \
      int slin = q * 256 + tid;                                            \
      u16x8 st;                                                            \
      st[0] = f2bf(fb[q][0].x); st[1] = f2bf(fb[q][0].y);                  \
      st[2] = f2bf(fb[q][0].z); st[3] = f2bf(fb[q][0].w);                  \
      st[4] = f2bf(fb[q][1].x); st[5] = f2bf(fb[q][1].y);                  \
      st[6] = f2bf(fb[q][1].z); st[7] = f2bf(fb[q][1].w);                  \
      *(u16x8*)(Bs + slin * 8) = st;                                       \
    }                                                                      \
  }

  f32x4 acc[8][4] = {};

  // prologue: B(0) -> regs, A(0) -> As[0]
  LOAD_B(0)
  STAGE_A(0, 0)

#pragma unroll
  for (int kt = 0; kt < 7; ++kt) {
    int cur = kt & 1;
    // consume B(kt) regs (compiler emits exact vmcnt for fb), write LDS image
    WRITE_B()
    if (kt < 6) {
      LOAD_B((kt + 1) * 64)      // B(kt+1) -> regs, in flight across MFMA phase
      STAGE_A(kt + 1, cur ^ 1)   // A(kt+1) -> other LDS buffer, in flight
    }
    __builtin_amdgcn_sched_barrier(0);
    // A(kt) is 16 vmem ops old (B(kt+1) x8 + A(kt+1) x8 issued after it);
    // lgkmcnt(0) makes this wave's Bs writes visible before the barrier.
    if (kt < 6) asm volatile("s_waitcnt vmcnt(16) lgkmcnt(0)" ::: "memory");
    else        asm volatile("s_waitcnt vmcnt(0) lgkmcnt(0)" ::: "memory");
    __builtin_amdgcn_sched_barrier(0);
    __builtin_amdgcn_s_barrier();
    __builtin_amdgcn_sched_barrier(0);

    __builtin_amdgcn_s_setprio(1);
#pragma unroll
    for (int s = 0; s < 2; ++s) {
      bf16x8 bfr[4];
#pragma unroll
      for (int j = 0; j < 4; ++j) {
        int bc = cbase + j * 16 + m16;
        bfr[j] = *(const bf16x8*)(Bs + bc * 64 + (((s * 4 + quad) ^ (bc & 7)) << 3));
      }
#pragma unroll
      for (int i = 0; i < 8; ++i) {
        int ar = rbase + i * 16 + m16;
        bf16x8 af = *(const bf16x8*)(As[cur] + ar * 64 + (((s * 4 + quad) ^ (ar & 7)) << 3));
#pragma unroll
        for (int j = 0; j < 4; ++j)
          acc[i][j] = __builtin_amdgcn_mfma_f32_16x16x32_bf16(af, bfr[j], acc[i][j], 0, 0, 0);
      }
    }
    __builtin_amdgcn_s_setprio(0);
    __builtin_amdgcn_sched_barrier(0);
    if (kt < 6) {
      __builtin_amdgcn_s_barrier();   // Bs/As[cur^1] reads done before next overwrite
      __builtin_amdgcn_sched_barrier(0);
    }
  }
#undef LOAD_B
#undef STAGE_A
#undef WRITE_B

#pragma unroll
  for (int i = 0; i < 8; ++i) {
#pragma unroll
    for (int j = 0; j < 4; ++j) {
      int col = nt * 128 + cbase + j * 16 + m16;
      if (col < N_ENT) {
        int row0 = mt * 256 + rbase + i * 16 + quad * 4;
#pragma unroll
        for (int rr = 0; rr < 4; ++rr)
          C[(size_t)(row0 + rr) * N_ENT + col] = acc[i][j][rr];
      }
    }
  }
}

extern "C" void kernel_launch(void* const* d_in, const int* in_sizes, int n_in,
                              void* d_out, int out_size, void* d_ws, size_t ws_size,
                              hipStream_t stream) {
  const float* e1   = (const float*)d_in[0];
  const float* rel  = (const float*)d_in[1];
  const float* entw = (const float*)d_in[2];
  const float* fc1w = (const float*)d_in[3];
  const float* fc1b = (const float*)d_in[4];
  const float* fcw  = (const float*)d_in[5];
  // d_in[6] = fc_b: constant per output feature -> cancels under bn2 mean subtraction
  const float* bn0g = (const float*)d_in[7];
  const float* bn0b = (const float*)d_in[8];
  const float* bn1g = (const float*)d_in[9];
  // d_in[10] = bn1_b: beta term is constant per k -> cancels under bn2 mean subtraction
  const float* bn2g = (const float*)d_in[11];
  const float* bn2b = (const float*)d_in[12];
  float* out = (float*)d_out;

  char* ws = (char*)d_ws;
  size_t off = 0;
  auto alloc = [&](size_t bytes) -> void* {
    off = (off + 255) & ~(size_t)255;
    void* p = ws + off;
    off += bytes;
    return p;
  };
  float* stats    = (float*)alloc(16 * 4);
  float* part0    = (float*)alloc(512 * 4);
  float* kbuf     = (float*)alloc((size_t)B_SZ * 288 * 4);
  float* partial1 = (float*)alloc((size_t)B_SZ * 64 * 4);
  float* alphaK   = (float*)alloc((size_t)K_FC * 4);
  u16*   convA    = (u16*)alloc((size_t)B_SZ * K_FC * 2);
  u16*   fcwb     = (u16*)alloc((size_t)NPAD_FC * K_FC * 2);
  float* part2    = (float*)alloc((size_t)SPLIT_FC * B_SZ * NPAD_FC * 4);
  u16*   hfin     = (u16*)alloc((size_t)B_SZ * KPAD_H * 2);

  red0<<<256, 256, 0, stream>>>(e1, part0);
  // fc1 GEMM with fused bn0-combine (block 0 tail)
  fc1_gemm<<<dim3(16, 5), 256, 0, stream>>>(rel, fc1w, fc1b, kbuf, part0, bn0g, bn0b, stats);
  conv_kernel<<<B_SZ, 256, 0, stream>>>(e1, stats, kbuf, convA, partial1);
  comb1<<<1, 256, 0, stream>>>(partial1, bn1g, alphaK);
  cvt_fcw<<<3136, 256, 0, stream>>>(fcw, alphaK, fcwb);
  // fc GEMM: M=1024, N=512(pad of 400), K=12544 -> split-K=14 deterministic partials
  gemm_bt<<<8 * 4 * SPLIT_FC, 256, 0, stream>>>(convA, fcwb, part2, K_FC, 8, 4, 196, 14,
                                                (long)NPAD_FC, NPAD_FC, (long)B_SZ * NPAD_FC);
  bn2_kernel<<<KPAD_H / 16, 256, 0, stream>>>(part2, bn2g, bn2b, hfin);
  // final GEMM v2: M=1024 (4 tiles of 256), N=50048 (391 tiles of 128), K=448,
  // XCD-swizzled, pipelined, fused f32->bf16 B staging
  gemm_ent<<<8 * 4 * 49, 256, 0, stream>>>(hfin, entw, out);
}